// Round 1
// baseline (800.078 us; speedup 1.0000x reference)
//
#include <hip/hip_runtime.h>

typedef unsigned int u32;
typedef unsigned long long u64;

#define A_TOT    159882
#define BS       2
#define NSEL     4507
#define NSORT    8192
#define CAND_CAP 4096
#define KTOP     1000

// ---- workspace layout (bytes) ----
static const size_t HIST_OFF  = 0;          // u32[10*65536] = 2,621,440
static const size_t CUT_OFF   = 2621440;    // u32[10]
static const size_t CCNT_OFF  = 2621504;    // u32[10]
static const size_t MAXC_OFF  = 2621568;    // u32[2]
static const size_t ZERO_BYTES= 2621632;    // memset [0, ZERO_BYTES)
static const size_t CAND_OFF  = 2621696;    // u64[10*4096]
static const size_t SELI_OFF  = 2949376;    // u32[2*4000]
static const size_t SORT_OFF  = 2981376;    // u64[2*8192]
static const size_t LPOS_OFF  = 3112448;    // u32[10*1000]
static const size_t LVAL_OFF  = 3152448;    // u32[10*1000]
static const size_t LBOX_OFF  = 3192448;    // float[10*1000*4] (16B aligned)
static const size_t MASK_OFF  = 3352448;    // u64[10*16000]
static const size_t KPOS_OFF  = 4632448;    // u32[2*4507]
// total ~4.67 MB

__device__ __forceinline__ int level_of(int a) {
  if (a < 120000) return 0;
  if (a < 150000) return 1;
  if (a < 157500) return 2;
  if (a < 159375) return 3;
  return 4;
}
__device__ __forceinline__ int level_k(int l) { return (l == 4) ? 507 : 1000; }

// monotone DEcreasing transform of score: smaller d == larger score.
// d(-inf) == 0xFF800000 exactly (used as the "invalid" marker).
__device__ __forceinline__ u32 dkey(float s) {
  u32 b = __float_as_uint(s);
  return (b & 0x80000000u) ? b : (~b & 0x7FFFFFFFu);
}

// bit-exact replica of reference decode + clip + min-size check.
// __f*_rn intrinsics forbid FMA contraction (HIP defaults to -ffp-contract=fast).
__device__ __forceinline__ void decode_clip(const float* __restrict__ pred,
                                            const float* __restrict__ anch,
                                            const float* __restrict__ vs,
                                            int b, int a,
                                            float& x1c, float& y1c, float& x2c, float& y2c,
                                            bool& valid) {
  const float* pp = pred + ((size_t)b * A_TOT + (size_t)a) * 4;
  const float* aa = anch + (size_t)a * 4;
  float ax1 = aa[0], ay1 = aa[1], ax2 = aa[2], ay2 = aa[3];
  float px = pp[0], py = pp[1], pw = pp[2], ph = pp[3];
  float aw  = __fsub_rn(ax2, ax1);
  float ah  = __fsub_rn(ay2, ay1);
  float acx = __fadd_rn(ax1, __fmul_rn(0.5f, aw));
  float acy = __fadd_rn(ay1, __fmul_rn(0.5f, ah));
  float cx  = __fadd_rn(acx, __fmul_rn(px, aw));
  float cy  = __fadd_rn(acy, __fmul_rn(py, ah));
  float w   = __fmul_rn(expf(pw), aw);
  float h   = __fmul_rn(expf(ph), ah);
  float x1  = __fsub_rn(cx, __fmul_rn(0.5f, w));
  float y1  = __fsub_rn(cy, __fmul_rn(0.5f, h));
  float x2  = __fadd_rn(x1, w);
  float y2  = __fadd_rn(y1, h);
  float Wv = vs[b * 2 + 0], Hv = vs[b * 2 + 1];
  x1c = fminf(fmaxf(x1, 0.0f), Wv);
  y1c = fminf(fmaxf(y1, 0.0f), Hv);
  x2c = fminf(fmaxf(x2, 0.0f), Wv);
  y2c = fminf(fmaxf(y2, 0.0f), Hv);
  valid = (__fsub_rn(x2c, x1c) > 0.001f) && (__fsub_rn(y2c, y1c) > 0.001f);
}

// ---------- 1) per-(image,level) 16-bit score histogram ----------
__global__ void k_hist(const float* __restrict__ obj, char* __restrict__ ws) {
  int t = blockIdx.x * blockDim.x + threadIdx.x;
  if (t >= BS * A_TOT) return;
  int b = t / A_TOT, a = t % A_TOT;
  int l = level_of(a);
  if (l >= 4) return;                      // level 4: all 507 selected, no top-k needed
  u32 d = dkey(obj[t]);
  u32* hist = (u32*)(ws + HIST_OFF);
  atomicAdd(&hist[(size_t)(b * 5 + l) * 65536 + (d >> 16)], 1u);
}

// ---------- 2) find cutoff bucket for top-1000 ----------
__global__ void k_cutoff(char* __restrict__ ws) {
  int b = blockIdx.x >> 2, l = blockIdx.x & 3;
  const u32* hist = (const u32*)(ws + HIST_OFF) + (size_t)(b * 5 + l) * 65536;
  __shared__ u32 part[256];
  int t = threadIdx.x;
  u32 s = 0;
  for (int q = 0; q < 256; ++q) s += hist[t * 256 + q];
  part[t] = s;
  __syncthreads();
  if (t == 0) {
    u32 run = 0; int cutb = 65535;
    for (int c = 0; c < 256; ++c) {
      if (run + part[c] >= KTOP) {
        for (int q = 0; q < 256; ++q) {
          run += hist[c * 256 + q];
          if (run >= KTOP) { cutb = c * 256 + q; break; }
        }
        break;
      }
      run += part[c];
    }
    ((u32*)(ws + CUT_OFF))[b * 5 + l] = (u32)cutb;
  }
}

// ---------- 3) compact candidates at/above cutoff ----------
__global__ void k_compact(const float* __restrict__ obj, char* __restrict__ ws) {
  int t = blockIdx.x * blockDim.x + threadIdx.x;
  if (t >= BS * A_TOT) return;
  int b = t / A_TOT, a = t % A_TOT;
  int l = level_of(a);
  if (l >= 4) return;
  u32 d = dkey(obj[t]);
  u32 cut = ((const u32*)(ws + CUT_OFF))[b * 5 + l];
  if ((d >> 16) <= cut) {
    u32 slot = atomicAdd(&((u32*)(ws + CCNT_OFF))[b * 5 + l], 1u);
    if (slot < CAND_CAP) {
      u64* cand = (u64*)(ws + CAND_OFF) + (size_t)(b * 5 + l) * CAND_CAP;
      cand[slot] = ((u64)d << 32) | (u32)a;   // tie-break: ascending anchor idx
    }
  }
}

__device__ __forceinline__ void bitonic_u64(u64* arr, int N, int t, int nt) {
  for (int k = 2; k <= N; k <<= 1) {
    for (int j = k >> 1; j > 0; j >>= 1) {
      __syncthreads();
      for (int i = t; i < N; i += nt) {
        int ixj = i ^ j;
        if (ixj > i) {
          u64 x = arr[i], y = arr[ixj];
          bool up = ((i & k) == 0);
          if (up ? (x > y) : (x < y)) { arr[i] = y; arr[ixj] = x; }
        }
      }
    }
  }
  __syncthreads();
}

// ---------- 4) sort candidates, emit exact top-1000 anchor indices ----------
__global__ void k_sortcand(char* __restrict__ ws) {
  __shared__ u64 arr[CAND_CAP];
  int b = blockIdx.x >> 2, l = blockIdx.x & 3;
  int t = threadIdx.x, nt = blockDim.x;
  u32 cnt = ((const u32*)(ws + CCNT_OFF))[b * 5 + l];
  if (cnt > CAND_CAP) cnt = CAND_CAP;
  const u64* cand = (const u64*)(ws + CAND_OFF) + (size_t)(b * 5 + l) * CAND_CAP;
  for (int i = t; i < CAND_CAP; i += nt) arr[i] = (i < (int)cnt) ? cand[i] : ~0ull;
  bitonic_u64(arr, CAND_CAP, t, nt);
  u32* sel = (u32*)(ws + SELI_OFF) + (size_t)b * 4000 + (size_t)l * 1000;
  for (int i = t; i < KTOP; i += nt) sel[i] = (u32)arr[i];
}

// ---------- 5) build final sort keys for 4507 selected; track max coord ----------
__global__ void k_buildfinal(const float* __restrict__ pred, const float* __restrict__ obj,
                             const float* __restrict__ anch, const float* __restrict__ vs,
                             char* __restrict__ ws) {
  int t = blockIdx.x * blockDim.x + threadIdx.x;
  if (t >= BS * NSORT) return;
  int b = t >> 13, j = t & (NSORT - 1);
  u64* sortbuf = (u64*)(ws + SORT_OFF) + (size_t)b * NSORT;
  if (j >= NSEL) { sortbuf[j] = ~0ull; return; }
  int a;
  if (j < 4000) a = (int)((const u32*)(ws + SELI_OFF))[(size_t)b * 4000 + j];
  else          a = 159375 + (j - 4000);     // level 4: all anchors
  float x1, y1, x2, y2; bool valid;
  decode_clip(pred, anch, vs, b, a, x1, y1, x2, y2, valid);
  float m = fmaxf(fmaxf(x1, y1), fmaxf(x2, y2));     // clipped coords >= 0
  atomicMax((u32*)(ws + MAXC_OFF) + b, __float_as_uint(m));
  float s = obj[(size_t)b * A_TOT + a];
  u32 d = valid ? dkey(s) : 0xFF800000u;             // invalid -> score=-inf
  sortbuf[j] = ((u64)d << 32) | (u32)a;
}

// ---------- 6) global stable sort (desc score, asc index) per image ----------
__global__ void k_sortfinal(char* __restrict__ ws) {
  __shared__ u64 arr[NSORT];   // 64 KB
  int b = blockIdx.x;
  int t = threadIdx.x, nt = blockDim.x;
  u64* sortbuf = (u64*)(ws + SORT_OFF) + (size_t)b * NSORT;
  for (int i = t; i < NSORT; i += nt) arr[i] = sortbuf[i];
  bitonic_u64(arr, NSORT, t, nt);
  for (int i = t; i < NSORT; i += nt) sortbuf[i] = arr[i];
}

// ---------- 7) per-level ordered compaction of the sorted list ----------
__global__ void k_lvlcompact(const float* __restrict__ pred, const float* __restrict__ anch,
                             const float* __restrict__ vs, char* __restrict__ ws) {
  int b = blockIdx.x / 5, l = blockIdx.x % 5;
  int lane = threadIdx.x;
  const u64* sortbuf = (const u64*)(ws + SORT_OFF) + (size_t)b * NSORT;
  u32* lpos   = (u32*)(ws + LPOS_OFF) + (size_t)(b * 5 + l) * 1000;
  u32* lval   = (u32*)(ws + LVAL_OFF) + (size_t)(b * 5 + l) * 1000;
  float* lbox = (float*)(ws + LBOX_OFF) + (size_t)(b * 5 + l) * 4000;
  float M = __uint_as_float(((const u32*)(ws + MAXC_OFF))[b]);
  float maxc = __fadd_rn(M, 1.0f);
  float off = __fmul_rn((float)l, maxc);  // replicate reference offset arithmetic exactly
  int base = 0;
  for (int j0 = 0; j0 < NSEL; j0 += 64) {
    int j = j0 + lane;
    bool inb = j < NSEL;
    u64 key = inb ? sortbuf[j] : ~0ull;
    int a = (int)(u32)key;
    bool prd = inb && (level_of(a) == l);
    u64 m = __ballot(prd);
    int r = base + __popcll(m & ((1ull << lane) - 1ull));
    if (prd) {
      lpos[r] = (u32)j;
      lval[r] = ((u32)(key >> 32) != 0xFF800000u) ? 1u : 0u;
      float x1, y1, x2, y2; bool valid;
      decode_clip(pred, anch, vs, b, a, x1, y1, x2, y2, valid);
      lbox[r * 4 + 0] = __fadd_rn(x1, off);
      lbox[r * 4 + 1] = __fadd_rn(y1, off);
      lbox[r * 4 + 2] = __fadd_rn(x2, off);
      lbox[r * 4 + 3] = __fadd_rn(y2, off);
    }
    base += __popcll(m);
  }
}

// ---------- 8) suppression-bitmask build (grid-parallel) ----------
__global__ void k_mask(char* __restrict__ ws) {
  int t = blockIdx.x * blockDim.x + threadIdx.x;  // 2*5*1000*16
  if (t >= 160000) return;
  int w = t & 15;
  int rest = t >> 4;
  int i = rest % 1000;
  int l = (rest / 1000) % 5;
  int b = rest / 5000;
  int n = level_k(l);
  int W = (n + 63) >> 6;
  if (i >= n || w >= W) return;
  const float* lbox = (const float*)(ws + LBOX_OFF) + (size_t)(b * 5 + l) * 4000;
  float4 bi = ((const float4*)lbox)[i];
  float ai = __fmul_rn(__fsub_rn(bi.z, bi.x), __fsub_rn(bi.w, bi.y));
  u64 word = 0;
  int j0 = w << 6;
  int jn = min(64, n - j0);
  for (int jj = 0; jj < jn; ++jj) {
    float4 bj = ((const float4*)lbox)[j0 + jj];
    float xx1 = fmaxf(bi.x, bj.x);
    float yy1 = fmaxf(bi.y, bj.y);
    float xx2 = fminf(bi.z, bj.z);
    float yy2 = fminf(bi.w, bj.w);
    float iw = fmaxf(__fsub_rn(xx2, xx1), 0.0f);
    float ih = fmaxf(__fsub_rn(yy2, yy1), 0.0f);
    float inter = __fmul_rn(iw, ih);
    float aj = __fmul_rn(__fsub_rn(bj.z, bj.x), __fsub_rn(bj.w, bj.y));
    float den = __fadd_rn(__fsub_rn(__fadd_rn(ai, aj), inter), 1e-9f);
    float iou = __fdiv_rn(inter, den);
    if (iou > 0.7f) word |= (1ull << jj);
  }
  ((u64*)(ws + MASK_OFF))[(size_t)(b * 5 + l) * 16000 + (size_t)i * W + w] = word;
}

// ---------- 9) wave-sequential greedy scan (one wave per image,level) ----------
__global__ void k_scan(char* __restrict__ ws) {
  __shared__ u64 ldsm[2176];    // 128 rows x 16 words + lookahead pad
  __shared__ u64 ldsk[16];
  int b = blockIdx.x / 5, l = blockIdx.x % 5;
  int lane = threadIdx.x;
  int n = level_k(l);
  int W = (n + 63) >> 6;
  const u64* maskg = (const u64*)(ws + MASK_OFF) + (size_t)(b * 5 + l) * 16000;
  const u32* lval = (const u32*)(ws + LVAL_OFF) + (size_t)(b * 5 + l) * 1000;
  const u32* lpos = (const u32*)(ws + LPOS_OFF) + (size_t)(b * 5 + l) * 1000;
  u32* kpos = (u32*)(ws + KPOS_OFF) + (size_t)b * NSEL;

  u64 removed = 0, keepw = 0;                 // lane w<W owns word w
  for (int c = 0; c < W; ++c) {               // removed init = ~valid
    int r = (c << 6) + lane;
    bool v = (r < n) && (lval[r] != 0);
    u64 bal = __ballot(v);
    if (lane == c) removed = ~bal;
  }

  int nb = (n + 127) >> 7;
  for (int bt = 0; bt < nb; ++bt) {
    int rb = bt << 7;
    int rows = min(128, n - rb);
    int words = rows * W;
    __syncthreads();
    for (int idx = lane; idx < words; idx += 64)
      ldsm[idx] = maskg[(size_t)rb * W + idx];
    __syncthreads();
    u64 cur[4];
#pragma unroll
    for (int d = 0; d < 4; ++d) {
      int rr = (d < rows) ? d : (rows - 1);
      cur[d] = ldsm[rr * W + lane];
    }
    for (int r0 = 0; r0 < rows; r0 += 4) {
      u64 nxt[4];
#pragma unroll
      for (int d = 0; d < 4; ++d) {            // depth-4 LDS lookahead
        int rr = r0 + 4 + d;
        rr = (rr < rows) ? rr : (rows - 1);
        nxt[d] = ldsm[rr * W + lane];
      }
#pragma unroll
      for (int d = 0; d < 4; ++d) {
        int r = r0 + d;
        if (r < rows) {
          int i = rb + r;
          int wi = i >> 6, bi2 = i & 63;
          bool mine = (lane == wi) && ((removed >> bi2) & 1ull);
          if (__ballot(mine) == 0ull) {        // kept: suppress its row
            removed |= cur[d];
            if (lane == wi) keepw |= (1ull << bi2);
          }
        }
      }
#pragma unroll
      for (int d = 0; d < 4; ++d) cur[d] = nxt[d];
    }
  }
  if (lane < 16) ldsk[lane] = keepw;
  __syncthreads();
  for (int r = lane; r < n; r += 64) {
    u32 bit = (u32)((ldsk[r >> 6] >> (r & 63)) & 1ull);
    kpos[lpos[r]] = bit;
  }
}

// ---------- 10) rank kept entries, write outputs ----------
__global__ void k_finalize(const float* __restrict__ pred, const float* __restrict__ obj,
                           const float* __restrict__ anch, const float* __restrict__ vs,
                           float* __restrict__ out, char* __restrict__ ws) {
  int b = blockIdx.x;
  int lane = threadIdx.x;
  const u32* kpos = (const u32*)(ws + KPOS_OFF) + (size_t)b * NSEL;
  const u64* sortbuf = (const u64*)(ws + SORT_OFF) + (size_t)b * NSORT;
  int base = 0;
  for (int j0 = 0; j0 < NSEL; j0 += 64) {
    int j = j0 + lane;
    bool inb = j < NSEL;
    bool kp = inb && (kpos[j] != 0);
    u64 m = __ballot(kp);
    int rank = base + __popcll(m & ((1ull << lane) - 1ull));
    if (kp && rank < KTOP) {
      u64 key = sortbuf[j];
      int a = (int)(u32)key;
      float x1, y1, x2, y2; bool valid;
      decode_clip(pred, anch, vs, b, a, x1, y1, x2, y2, valid);
      float s = obj[(size_t)b * A_TOT + a];
      float* ob = out + ((size_t)b * KTOP + rank) * 4;
      ob[0] = x1; ob[1] = y1; ob[2] = x2; ob[3] = y2;
      out[8000 + (size_t)b * KTOP + rank] = s;
    }
    base += __popcll(m);
  }
}

extern "C" void kernel_launch(void* const* d_in, const int* in_sizes, int n_in,
                              void* d_out, int out_size, void* d_ws, size_t ws_size,
                              hipStream_t stream) {
  const float* pred = (const float*)d_in[0];   // (2, A, 4)
  const float* obj  = (const float*)d_in[1];   // (2, A, 1)
  const float* anch = (const float*)d_in[2];   // (A, 4)
  const float* vs   = (const float*)d_in[3];   // (2, 2)
  float* out = (float*)d_out;                  // 8000 boxes + 2000 scores
  char* ws = (char*)d_ws;

  (void)in_sizes; (void)n_in; (void)out_size; (void)ws_size;

  hipMemsetAsync(ws, 0, ZERO_BYTES, stream);           // hist + counters + maxc
  hipMemsetAsync(d_out, 0, 10000 * sizeof(float), stream);

  int gBA = (BS * A_TOT + 255) / 256;
  k_hist      <<<gBA, 256, 0, stream>>>(obj, ws);
  k_cutoff    <<<8,   256, 0, stream>>>(ws);
  k_compact   <<<gBA, 256, 0, stream>>>(obj, ws);
  k_sortcand  <<<8,   512, 0, stream>>>(ws);
  k_buildfinal<<<(BS * NSORT) / 256, 256, 0, stream>>>(pred, obj, anch, vs, ws);
  k_sortfinal <<<2,  1024, 0, stream>>>(ws);
  k_lvlcompact<<<10,   64, 0, stream>>>(pred, anch, vs, ws);
  k_mask      <<<625, 256, 0, stream>>>(ws);
  k_scan      <<<10,   64, 0, stream>>>(ws);
  k_finalize  <<<2,    64, 0, stream>>>(pred, obj, anch, vs, out, ws);
}

// Round 2
// 562.444 us; speedup vs baseline: 1.4225x; 1.4225x over previous
//
#include <hip/hip_runtime.h>

typedef unsigned int u32;
typedef unsigned long long u64;

#define A_TOT    159882
#define BS       2
#define NSEL     4507
#define NSORT    8192
#define CAND_CAP 4096
#define KTOP     1000

// ---- workspace layout (bytes) ----
static const size_t HIST_OFF   = 0;          // u32[10*65536] = 2,621,440
static const size_t CUT_OFF    = 2621440;    // u32[10]
static const size_t CCNT_OFF   = 2621504;    // u32[10]
static const size_t MAXC_OFF   = 2621568;    // u32[2]
static const size_t CHUNKANY_OFF = 2621632;  // u64[10*16] = 1280
static const size_t ZERO_BYTES = 2622912;    // memset [0, ZERO_BYTES)
static const size_t CAND_OFF   = 2622912;    // u64[10*4096]
static const size_t SELI_OFF   = 2950592;    // u32[2*4000]
static const size_t SORT_OFF   = 2982592;    // u64[2*8192]
static const size_t LPOS_OFF   = 3113664;    // u32[10*1000]
static const size_t LVAL_OFF   = 3153664;    // u32[10*1000]
static const size_t LBOX_OFF   = 3193664;    // float[10*1000*4] (16B aligned)
static const size_t MASK_OFF   = 3353664;    // u64[10*16000]
static const size_t KPOS_OFF   = 4633664;    // u32[2*4507]
// total ~4.67 MB

__device__ __forceinline__ int level_of(int a) {
  if (a < 120000) return 0;
  if (a < 150000) return 1;
  if (a < 157500) return 2;
  if (a < 159375) return 3;
  return 4;
}
__device__ __forceinline__ int level_k(int l) { return (l == 4) ? 507 : 1000; }

// monotone DEcreasing transform of score: smaller d == larger score.
// d(-inf) == 0xFF800000 exactly (used as the "invalid" marker).
__device__ __forceinline__ u32 dkey(float s) {
  u32 b = __float_as_uint(s);
  return (b & 0x80000000u) ? b : (~b & 0x7FFFFFFFu);
}

// bit-exact replica of reference decode + clip + min-size check.
__device__ __forceinline__ void decode_clip(const float* __restrict__ pred,
                                            const float* __restrict__ anch,
                                            const float* __restrict__ vs,
                                            int b, int a,
                                            float& x1c, float& y1c, float& x2c, float& y2c,
                                            bool& valid) {
  const float* pp = pred + ((size_t)b * A_TOT + (size_t)a) * 4;
  const float* aa = anch + (size_t)a * 4;
  float ax1 = aa[0], ay1 = aa[1], ax2 = aa[2], ay2 = aa[3];
  float px = pp[0], py = pp[1], pw = pp[2], ph = pp[3];
  float aw  = __fsub_rn(ax2, ax1);
  float ah  = __fsub_rn(ay2, ay1);
  float acx = __fadd_rn(ax1, __fmul_rn(0.5f, aw));
  float acy = __fadd_rn(ay1, __fmul_rn(0.5f, ah));
  float cx  = __fadd_rn(acx, __fmul_rn(px, aw));
  float cy  = __fadd_rn(acy, __fmul_rn(py, ah));
  float w   = __fmul_rn(expf(pw), aw);
  float h   = __fmul_rn(expf(ph), ah);
  float x1  = __fsub_rn(cx, __fmul_rn(0.5f, w));
  float y1  = __fsub_rn(cy, __fmul_rn(0.5f, h));
  float x2  = __fadd_rn(x1, w);
  float y2  = __fadd_rn(y1, h);
  float Wv = vs[b * 2 + 0], Hv = vs[b * 2 + 1];
  x1c = fminf(fmaxf(x1, 0.0f), Wv);
  y1c = fminf(fmaxf(y1, 0.0f), Hv);
  x2c = fminf(fmaxf(x2, 0.0f), Wv);
  y2c = fminf(fmaxf(y2, 0.0f), Hv);
  valid = (__fsub_rn(x2c, x1c) > 0.001f) && (__fsub_rn(y2c, y1c) > 0.001f);
}

// ---------- 1) per-(image,level) 16-bit score histogram ----------
__global__ void k_hist(const float* __restrict__ obj, char* __restrict__ ws) {
  int t = blockIdx.x * blockDim.x + threadIdx.x;
  if (t >= BS * A_TOT) return;
  int b = t / A_TOT, a = t % A_TOT;
  int l = level_of(a);
  if (l >= 4) return;                      // level 4: all 507 selected
  u32 d = dkey(obj[t]);
  u32* hist = (u32*)(ws + HIST_OFF);
  atomicAdd(&hist[(size_t)(b * 5 + l) * 65536 + (d >> 16)], 1u);
}

// ---------- 2) cutoff bucket for top-1000 (parallel prefix scans) ----------
__global__ void k_cutoff(char* __restrict__ ws) {
  int b = blockIdx.x >> 2, l = blockIdx.x & 3;
  const u32* hist = (const u32*)(ws + HIST_OFF) + (size_t)(b * 5 + l) * 65536;
  __shared__ u32 incl[256];
  __shared__ u32 sc_c, sc_base;
  int t = threadIdx.x;
  u32 s = 0;
  for (int q = 0; q < 256; ++q) s += hist[t * 256 + q];
  incl[t] = s; __syncthreads();
  for (int d = 1; d < 256; d <<= 1) {
    u32 v = (t >= d) ? incl[t - d] : 0u; __syncthreads();
    incl[t] += v; __syncthreads();
  }
  if (incl[t] >= KTOP && (t == 0 || incl[t - 1] < KTOP)) {
    sc_c = (u32)t; sc_base = (t == 0) ? 0u : incl[t - 1];
  }
  __syncthreads();
  u32 c = sc_c, base = sc_base;
  u32 v2 = hist[c * 256 + t];
  __syncthreads();
  incl[t] = v2; __syncthreads();
  for (int d = 1; d < 256; d <<= 1) {
    u32 v = (t >= d) ? incl[t - d] : 0u; __syncthreads();
    incl[t] += v; __syncthreads();
  }
  if (base + incl[t] >= KTOP && (t == 0 || base + incl[t - 1] < KTOP))
    ((u32*)(ws + CUT_OFF))[b * 5 + l] = c * 256 + (u32)t;
}

// ---------- 3) compact candidates at/above cutoff ----------
__global__ void k_compact(const float* __restrict__ obj, char* __restrict__ ws) {
  int t = blockIdx.x * blockDim.x + threadIdx.x;
  if (t >= BS * A_TOT) return;
  int b = t / A_TOT, a = t % A_TOT;
  int l = level_of(a);
  if (l >= 4) return;
  u32 d = dkey(obj[t]);
  u32 cut = ((const u32*)(ws + CUT_OFF))[b * 5 + l];
  if ((d >> 16) <= cut) {
    u32 slot = atomicAdd(&((u32*)(ws + CCNT_OFF))[b * 5 + l], 1u);
    if (slot < CAND_CAP) {
      u64* cand = (u64*)(ws + CAND_OFF) + (size_t)(b * 5 + l) * CAND_CAP;
      cand[slot] = ((u64)d << 32) | (u32)a;   // tie-break: ascending anchor idx
    }
  }
}

__device__ __forceinline__ void bitonic_u64(u64* arr, int N, int t, int nt) {
  for (int k = 2; k <= N; k <<= 1) {
    for (int j = k >> 1; j > 0; j >>= 1) {
      __syncthreads();
      for (int i = t; i < N; i += nt) {
        int ixj = i ^ j;
        if (ixj > i) {
          u64 x = arr[i], y = arr[ixj];
          bool up = ((i & k) == 0);
          if (up ? (x > y) : (x < y)) { arr[i] = y; arr[ixj] = x; }
        }
      }
    }
  }
  __syncthreads();
}

// ---------- 4) sort candidates, emit exact top-1000 anchor indices ----------
__global__ void k_sortcand(char* __restrict__ ws) {
  __shared__ u64 arr[CAND_CAP];
  int b = blockIdx.x >> 2, l = blockIdx.x & 3;
  int t = threadIdx.x, nt = blockDim.x;
  u32 cnt = ((const u32*)(ws + CCNT_OFF))[b * 5 + l];
  if (cnt > CAND_CAP) cnt = CAND_CAP;
  const u64* cand = (const u64*)(ws + CAND_OFF) + (size_t)(b * 5 + l) * CAND_CAP;
  for (int i = t; i < CAND_CAP; i += nt) arr[i] = (i < (int)cnt) ? cand[i] : ~0ull;
  bitonic_u64(arr, CAND_CAP, t, nt);
  u32* sel = (u32*)(ws + SELI_OFF) + (size_t)b * 4000 + (size_t)l * 1000;
  for (int i = t; i < KTOP; i += nt) sel[i] = (u32)arr[i];
}

// ---------- 5) build final sort keys; wave-reduced max coord ----------
__global__ void k_buildfinal(const float* __restrict__ pred, const float* __restrict__ obj,
                             const float* __restrict__ anch, const float* __restrict__ vs,
                             char* __restrict__ ws) {
  int t = blockIdx.x * blockDim.x + threadIdx.x;
  int b = t >> 13, j = t & (NSORT - 1);
  u64* sortbuf = (u64*)(ws + SORT_OFF) + (size_t)b * NSORT;
  float m = 0.0f;
  if (j < NSEL) {
    int a;
    if (j < 4000) a = (int)((const u32*)(ws + SELI_OFF))[(size_t)b * 4000 + j];
    else          a = 159375 + (j - 4000);     // level 4: all anchors
    float x1, y1, x2, y2; bool valid;
    decode_clip(pred, anch, vs, b, a, x1, y1, x2, y2, valid);
    m = fmaxf(fmaxf(x1, y1), fmaxf(x2, y2));   // clipped coords >= 0
    float s = obj[(size_t)b * A_TOT + a];
    u32 d = valid ? dkey(s) : 0xFF800000u;     // invalid -> score=-inf
    sortbuf[j] = ((u64)d << 32) | (u32)a;
  } else {
    sortbuf[j] = ~0ull;
  }
  // wave max-reduce, one atomic per wave (b is wave-uniform: 8192 j's per b)
  for (int off = 32; off; off >>= 1) m = fmaxf(m, __shfl_xor(m, off));
  if ((threadIdx.x & 63) == 0)
    atomicMax((u32*)(ws + MAXC_OFF) + b, __float_as_uint(m));
}

// ---------- 6) global stable sort (desc score, asc index) per image ----------
__global__ void k_sortfinal(char* __restrict__ ws) {
  __shared__ u64 arr[NSORT];   // 64 KB
  int b = blockIdx.x;
  int t = threadIdx.x, nt = blockDim.x;
  u64* sortbuf = (u64*)(ws + SORT_OFF) + (size_t)b * NSORT;
  for (int i = t; i < NSORT; i += nt) arr[i] = sortbuf[i];
  bitonic_u64(arr, NSORT, t, nt);
  for (int i = t; i < NSORT; i += nt) sortbuf[i] = arr[i];
}

// ---------- 7) per-level ordered compaction of the sorted list ----------
__global__ void k_lvlcompact(const float* __restrict__ pred, const float* __restrict__ anch,
                             const float* __restrict__ vs, char* __restrict__ ws) {
  int b = blockIdx.x / 5, l = blockIdx.x % 5;
  int lane = threadIdx.x;
  const u64* sortbuf = (const u64*)(ws + SORT_OFF) + (size_t)b * NSORT;
  u32* lpos   = (u32*)(ws + LPOS_OFF) + (size_t)(b * 5 + l) * 1000;
  u32* lval   = (u32*)(ws + LVAL_OFF) + (size_t)(b * 5 + l) * 1000;
  float* lbox = (float*)(ws + LBOX_OFF) + (size_t)(b * 5 + l) * 4000;
  float M = __uint_as_float(((const u32*)(ws + MAXC_OFF))[b]);
  float maxc = __fadd_rn(M, 1.0f);
  float off = __fmul_rn((float)l, maxc);  // replicate reference offset arithmetic
  int base = 0;
  for (int j0 = 0; j0 < NSEL; j0 += 64) {
    int j = j0 + lane;
    bool inb = j < NSEL;
    u64 key = inb ? sortbuf[j] : ~0ull;
    int a = (int)(u32)key;
    bool prd = inb && (level_of(a) == l);
    u64 m = __ballot(prd);
    int r = base + __popcll(m & ((1ull << lane) - 1ull));
    if (prd) {
      lpos[r] = (u32)j;
      lval[r] = ((u32)(key >> 32) != 0xFF800000u) ? 1u : 0u;
      float x1, y1, x2, y2; bool valid;
      decode_clip(pred, anch, vs, b, a, x1, y1, x2, y2, valid);
      lbox[r * 4 + 0] = __fadd_rn(x1, off);
      lbox[r * 4 + 1] = __fadd_rn(y1, off);
      lbox[r * 4 + 2] = __fadd_rn(x2, off);
      lbox[r * 4 + 3] = __fadd_rn(y2, off);
    }
    base += __popcll(m);
  }
}

// ---------- 8) suppression bitmask + per-chunk row-nonempty bitmap ----------
__global__ void k_mask(char* __restrict__ ws) {
  int t = blockIdx.x * blockDim.x + threadIdx.x;  // 2*5*1000*16
  if (t >= 160000) return;
  int w = t & 15;
  int rest = t >> 4;
  int i = rest % 1000;
  int l = (rest / 1000) % 5;
  int b = rest / 5000;
  int n = level_k(l);
  int W = (n + 63) >> 6;
  if (i >= n || w >= W) return;
  const float* lbox = (const float*)(ws + LBOX_OFF) + (size_t)(b * 5 + l) * 4000;
  float4 bi = ((const float4*)lbox)[i];
  float ai = __fmul_rn(__fsub_rn(bi.z, bi.x), __fsub_rn(bi.w, bi.y));
  u64 word = 0;
  int j0 = w << 6;
  int jn = min(64, n - j0);
  for (int jj = 0; jj < jn; ++jj) {
    float4 bj = ((const float4*)lbox)[j0 + jj];
    float xx1 = fmaxf(bi.x, bj.x);
    float yy1 = fmaxf(bi.y, bj.y);
    float xx2 = fminf(bi.z, bj.z);
    float yy2 = fminf(bi.w, bj.w);
    float iw = fmaxf(__fsub_rn(xx2, xx1), 0.0f);
    float ih = fmaxf(__fsub_rn(yy2, yy1), 0.0f);
    float inter = __fmul_rn(iw, ih);
    float aj = __fmul_rn(__fsub_rn(bj.z, bj.x), __fsub_rn(bj.w, bj.y));
    float den = __fadd_rn(__fsub_rn(__fadd_rn(ai, aj), inter), 1e-9f);
    float iou = __fdiv_rn(inter, den);
    if (iou > 0.7f) word |= (1ull << jj);
  }
  // zero the diagonal: reference only consults j<i, and keeping self-bit 0
  // lets the empty-diag fast path in k_scan fire.
  if (i >= j0 && i < j0 + 64) word &= ~(1ull << (i - j0));
  ((u64*)(ws + MASK_OFF))[(size_t)(b * 5 + l) * 16000 + (size_t)i * W + w] = word;
  if (word)
    atomicOr((u64*)(ws + CHUNKANY_OFF) + (size_t)(b * 5 + l) * 16 + (i >> 6),
             1ull << (i & 63));
}

// ---------- 9) chunked greedy scan with sparse fast path ----------
__global__ void k_scan(char* __restrict__ ws) {
  __shared__ u64 ldsk[16];
  int b = blockIdx.x / 5, l = blockIdx.x % 5;
  int lane = threadIdx.x;
  int n = level_k(l);
  int W = (n + 63) >> 6;
  const u64* maskg = (const u64*)(ws + MASK_OFF) + (size_t)(b * 5 + l) * 16000;
  const u64* chunkany = (const u64*)(ws + CHUNKANY_OFF) + (size_t)(b * 5 + l) * 16;
  const u32* lval = (const u32*)(ws + LVAL_OFF) + (size_t)(b * 5 + l) * 1000;
  const u32* lpos = (const u32*)(ws + LPOS_OFF) + (size_t)(b * 5 + l) * 1000;
  u32* kpos = (u32*)(ws + KPOS_OFF) + (size_t)b * NSEL;

  u64 removed = 0, keepw = 0;                 // lane w<W owns word w
  for (int c = 0; c < W; ++c) {               // removed init = ~valid
    int r = (c << 6) + lane;
    bool v = (r < n) && (lval[r] != 0);
    u64 bal = __ballot(v);
    if (lane == c) removed = ~bal;
  }

  int NC = (n + 63) >> 6;
  for (int c = 0; c < NC; ++c) {
    int rb = c << 6;
    int rows = min(64, n - rb);
    u64 rowsmask = (rows == 64) ? ~0ull : ((1ull << rows) - 1ull);
    u64 curw = __shfl(removed, c);            // word c of removed, broadcast
    u64 cand = ~curw & rowsmask;
    u64 anyrows = chunkany[c] & cand;
    u64 keptbits;
    if (anyrows == 0ull) {
      keptbits = cand;                        // fast path: nothing to suppress
    } else {
      u64 diag = (lane < rows) ? maskg[(size_t)(rb + lane) * W + c] : 0ull;
      u64 diagnz = __ballot(diag != 0ull);
      if ((diagnz & cand) == 0ull) {
        keptbits = cand;                      // no intra-chunk suppression
      } else {
        u64 remw = curw | ~rowsmask;          // branchless-ish scalar chain
        u64 kept = 0;
        for (int r = 0; r < rows; ++r) {
          u64 dr = __shfl(diag, r);           // uniform index -> readlane
          bool k = ((remw >> r) & 1ull) == 0ull;
          u64 sel = k ? ~0ull : 0ull;
          remw |= dr & sel;
          kept |= ((u64)(k ? 1 : 0)) << r;
        }
        keptbits = kept;
      }
      // cross-chunk update: OR full rows of kept rows that have bits
      u64 todo = keptbits & chunkany[c];
      while (todo) {
        int r = __builtin_ctzll(todo);
        todo &= todo - 1;
        u64 rowv = (lane < W) ? maskg[(size_t)(rb + r) * W + lane] : 0ull;
        removed |= rowv;
      }
    }
    if (lane == c) keepw |= keptbits;
  }
  if (lane < 16) ldsk[lane] = keepw;
  __syncthreads();
  for (int r = lane; r < n; r += 64) {
    u32 bit = (u32)((ldsk[r >> 6] >> (r & 63)) & 1ull);
    kpos[lpos[r]] = bit;
  }
}

// ---------- 10) rank kept entries, write outputs ----------
__global__ void k_finalize(const float* __restrict__ pred, const float* __restrict__ obj,
                           const float* __restrict__ anch, const float* __restrict__ vs,
                           float* __restrict__ out, char* __restrict__ ws) {
  int b = blockIdx.x;
  int lane = threadIdx.x;
  const u32* kpos = (const u32*)(ws + KPOS_OFF) + (size_t)b * NSEL;
  const u64* sortbuf = (const u64*)(ws + SORT_OFF) + (size_t)b * NSORT;
  int base = 0;
  for (int j0 = 0; j0 < NSEL; j0 += 64) {
    int j = j0 + lane;
    bool inb = j < NSEL;
    bool kp = inb && (kpos[j] != 0);
    u64 m = __ballot(kp);
    int rank = base + __popcll(m & ((1ull << lane) - 1ull));
    if (kp && rank < KTOP) {
      u64 key = sortbuf[j];
      int a = (int)(u32)key;
      float x1, y1, x2, y2; bool valid;
      decode_clip(pred, anch, vs, b, a, x1, y1, x2, y2, valid);
      float s = obj[(size_t)b * A_TOT + a];
      float* ob = out + ((size_t)b * KTOP + rank) * 4;
      ob[0] = x1; ob[1] = y1; ob[2] = x2; ob[3] = y2;
      out[8000 + (size_t)b * KTOP + rank] = s;
    }
    base += __popcll(m);
  }
}

extern "C" void kernel_launch(void* const* d_in, const int* in_sizes, int n_in,
                              void* d_out, int out_size, void* d_ws, size_t ws_size,
                              hipStream_t stream) {
  const float* pred = (const float*)d_in[0];   // (2, A, 4)
  const float* obj  = (const float*)d_in[1];   // (2, A, 1)
  const float* anch = (const float*)d_in[2];   // (A, 4)
  const float* vs   = (const float*)d_in[3];   // (2, 2)
  float* out = (float*)d_out;                  // 8000 boxes + 2000 scores
  char* ws = (char*)d_ws;

  (void)in_sizes; (void)n_in; (void)out_size; (void)ws_size;

  hipMemsetAsync(ws, 0, ZERO_BYTES, stream);   // hist + counters + chunkany
  hipMemsetAsync(d_out, 0, 10000 * sizeof(float), stream);

  int gBA = (BS * A_TOT + 255) / 256;
  k_hist      <<<gBA, 256, 0, stream>>>(obj, ws);
  k_cutoff    <<<8,   256, 0, stream>>>(ws);
  k_compact   <<<gBA, 256, 0, stream>>>(obj, ws);
  k_sortcand  <<<8,   512, 0, stream>>>(ws);
  k_buildfinal<<<(BS * NSORT) / 256, 256, 0, stream>>>(pred, obj, anch, vs, ws);
  k_sortfinal <<<2,  1024, 0, stream>>>(ws);
  k_lvlcompact<<<10,   64, 0, stream>>>(pred, anch, vs, ws);
  k_mask      <<<625, 256, 0, stream>>>(ws);
  k_scan      <<<10,   64, 0, stream>>>(ws);
  k_finalize  <<<2,    64, 0, stream>>>(pred, obj, anch, vs, out, ws);
}

// Round 3
// 403.725 us; speedup vs baseline: 1.9817x; 1.3931x over previous
//
#include <hip/hip_runtime.h>

typedef unsigned int u32;
typedef unsigned long long u64;

#define A_TOT    159882
#define BS       2
#define KTOP     1000
#define CAND_CAP 4096

// ---- workspace layout (bytes) ----
static const size_t HIST_OFF   = 0;           // u32[8*65536]
static const size_t CUT_OFF    = 2097152;     // u32[8]
static const size_t CCNT_OFF   = 2097184;     // u32[8]
static const size_t MAXC_OFF   = 2097216;     // u32[2]
static const size_t NV_OFF     = 2097224;     // u32[10]
static const size_t CHUNKANY_OFF = 2097264;   // u64[10*16]
static const size_t KB_OFF     = 2098544;     // u64[2*128]
static const size_t ZERO_BYTES = 2100592;
static const size_t CAND_OFF   = 2100592;     // u64[8*4096]
static const size_t LSORT_OFF  = 2362736;     // u64[10*1024]
static const size_t DBOX_OFF   = 2444656;     // float4[10*1024]
static const size_t DVAL_OFF   = 2608496;     // u32[10*1024]
static const size_t DSC_OFF    = 2649456;     // float[10*1024]
static const size_t LKEY2_OFF  = 2690416;     // u64[10*1024]
static const size_t LBOX_OFF   = 2772336;     // float4[10*1024]
static const size_t LSC_OFF    = 2936176;     // float[10*1024]
static const size_t RANK_OFF   = 2977136;     // u32[10*1024]
static const size_t GL_OFF     = 3018096;     // u32[2*4608]
static const size_t MASK_OFF   = 3054960;     // u64[10*16000]
// total ~4.34 MB

__device__ __forceinline__ int level_of(int a) {
  if (a < 120000) return 0;
  if (a < 150000) return 1;
  if (a < 157500) return 2;
  if (a < 159375) return 3;
  return 4;
}
__device__ __forceinline__ int level_n(int l) { return (l == 4) ? 507 : 1000; }

// monotone decreasing transform: smaller d == larger score; d(-inf)=0xFF800000
__device__ __forceinline__ u32 dkey(float s) {
  u32 b = __float_as_uint(s);
  return (b & 0x80000000u) ? b : (~b & 0x7FFFFFFFu);
}

// bit-exact replica of reference decode + clip + min-size check
__device__ __forceinline__ void decode_clip(const float* __restrict__ pred,
                                            const float* __restrict__ anch,
                                            const float* __restrict__ vs,
                                            int b, int a,
                                            float& x1c, float& y1c, float& x2c, float& y2c,
                                            bool& valid) {
  const float* pp = pred + ((size_t)b * A_TOT + (size_t)a) * 4;
  const float* aa = anch + (size_t)a * 4;
  float ax1 = aa[0], ay1 = aa[1], ax2 = aa[2], ay2 = aa[3];
  float px = pp[0], py = pp[1], pw = pp[2], ph = pp[3];
  float aw  = __fsub_rn(ax2, ax1);
  float ah  = __fsub_rn(ay2, ay1);
  float acx = __fadd_rn(ax1, __fmul_rn(0.5f, aw));
  float acy = __fadd_rn(ay1, __fmul_rn(0.5f, ah));
  float cx  = __fadd_rn(acx, __fmul_rn(px, aw));
  float cy  = __fadd_rn(acy, __fmul_rn(py, ah));
  float w   = __fmul_rn(expf(pw), aw);
  float h   = __fmul_rn(expf(ph), ah);
  float x1  = __fsub_rn(cx, __fmul_rn(0.5f, w));
  float y1  = __fsub_rn(cy, __fmul_rn(0.5f, h));
  float x2  = __fadd_rn(x1, w);
  float y2  = __fadd_rn(y1, h);
  float Wv = vs[b * 2 + 0], Hv = vs[b * 2 + 1];
  x1c = fminf(fmaxf(x1, 0.0f), Wv);
  y1c = fminf(fmaxf(y1, 0.0f), Hv);
  x2c = fminf(fmaxf(x2, 0.0f), Wv);
  y2c = fminf(fmaxf(y2, 0.0f), Hv);
  valid = (__fsub_rn(x2c, x1c) > 0.001f) && (__fsub_rn(y2c, y1c) > 0.001f);
}

// ---------- 1) per-(image,level<4) 16-bit score histogram ----------
__global__ void k_hist(const float* __restrict__ obj, char* __restrict__ ws) {
  int t = blockIdx.x * blockDim.x + threadIdx.x;
  if (t >= BS * A_TOT) return;
  int b = t / A_TOT, a = t % A_TOT;
  int l = level_of(a);
  if (l >= 4) return;
  u32 d = dkey(obj[t]);
  atomicAdd((u32*)(ws + HIST_OFF) + (size_t)(b * 4 + l) * 65536 + (d >> 16), 1u);
}

// ---------- 2) cutoff bucket for top-1000 (parallel prefix scans) ----------
__global__ void k_cutoff(char* __restrict__ ws) {
  int b = blockIdx.x >> 2, l = blockIdx.x & 3;
  const u32* hist = (const u32*)(ws + HIST_OFF) + (size_t)(b * 4 + l) * 65536;
  __shared__ u32 incl[256];
  __shared__ u32 sc_c, sc_base;
  int t = threadIdx.x;
  u32 s = 0;
  for (int q = 0; q < 256; ++q) s += hist[t * 256 + q];
  incl[t] = s; __syncthreads();
  for (int d = 1; d < 256; d <<= 1) {
    u32 v = (t >= d) ? incl[t - d] : 0u; __syncthreads();
    incl[t] += v; __syncthreads();
  }
  if (incl[t] >= KTOP && (t == 0 || incl[t - 1] < KTOP)) {
    sc_c = (u32)t; sc_base = (t == 0) ? 0u : incl[t - 1];
  }
  __syncthreads();
  u32 c = sc_c, base = sc_base;
  u32 v2 = hist[c * 256 + t];
  __syncthreads();
  incl[t] = v2; __syncthreads();
  for (int d = 1; d < 256; d <<= 1) {
    u32 v = (t >= d) ? incl[t - d] : 0u; __syncthreads();
    incl[t] += v; __syncthreads();
  }
  if (base + incl[t] >= KTOP && (t == 0 || base + incl[t - 1] < KTOP))
    ((u32*)(ws + CUT_OFF))[b * 4 + l] = c * 256 + (u32)t;
}

// ---------- 3) compact candidates at/below cutoff key ----------
__global__ void k_compact(const float* __restrict__ obj, char* __restrict__ ws) {
  int t = blockIdx.x * blockDim.x + threadIdx.x;
  if (t >= BS * A_TOT) return;
  int b = t / A_TOT, a = t % A_TOT;
  int l = level_of(a);
  if (l >= 4) return;
  u32 d = dkey(obj[t]);
  u32 cut = ((const u32*)(ws + CUT_OFF))[b * 4 + l];
  if ((d >> 16) <= cut) {
    u32 slot = atomicAdd((u32*)(ws + CCNT_OFF) + (b * 4 + l), 1u);
    if (slot < CAND_CAP)
      ((u64*)(ws + CAND_OFF))[(size_t)(b * 4 + l) * CAND_CAP + slot] =
          ((u64)d << 32) | (u32)a;
  }
}

__device__ __forceinline__ void bitonic_u64(u64* arr, int N, int t, int nt) {
  for (int k = 2; k <= N; k <<= 1) {
    for (int j = k >> 1; j > 0; j >>= 1) {
      __syncthreads();
      for (int i = t; i < N; i += nt) {
        int ixj = i ^ j;
        if (ixj > i) {
          u64 x = arr[i], y = arr[ixj];
          bool up = ((i & k) == 0);
          if (up ? (x > y) : (x < y)) { arr[i] = y; arr[ixj] = x; }
        }
      }
    }
  }
  __syncthreads();
}

// ---------- 4) per-(image,level) sorted key lists (dynamic N) ----------
__global__ void k_sortcand(const float* __restrict__ obj, char* __restrict__ ws) {
  __shared__ u64 arr[CAND_CAP];   // 32 KB
  int P = blockIdx.x, b = P / 5, l = P % 5;
  int t = threadIdx.x, nt = blockDim.x;
  int N, n_out;
  if (l < 4) {
    u32 cnt = ((const u32*)(ws + CCNT_OFF))[b * 4 + l];
    if (cnt > CAND_CAP) cnt = CAND_CAP;
    N = 1024; while (N < (int)cnt) N <<= 1;
    const u64* cand = (const u64*)(ws + CAND_OFF) + (size_t)(b * 4 + l) * CAND_CAP;
    for (int i = t; i < N; i += nt) arr[i] = (i < (int)cnt) ? cand[i] : ~0ull;
    n_out = KTOP;
  } else {
    N = 512;
    for (int i = t; i < N; i += nt) {
      if (i < 507) {
        int a = 159375 + i;
        u32 d = dkey(obj[(size_t)b * A_TOT + a]);
        arr[i] = ((u64)d << 32) | (u32)a;
      } else arr[i] = ~0ull;
    }
    n_out = 507;
  }
  bitonic_u64(arr, N, t, nt);
  u64* lsort = (u64*)(ws + LSORT_OFF) + (size_t)P * 1024;
  for (int i = t; i < n_out; i += nt) lsort[i] = arr[i];
}

// ---------- 5) fully-parallel decode of all selected entries ----------
__global__ void k_decode(const float* __restrict__ pred, const float* __restrict__ obj,
                         const float* __restrict__ anch, const float* __restrict__ vs,
                         char* __restrict__ ws) {
  int t = blockIdx.x * blockDim.x + threadIdx.x;   // 10*1024
  int P = t >> 10, j = t & 1023;
  int b = P / 5, l = P % 5;
  int n = level_n(l);
  float m = 0.0f;
  if (j < n) {
    u64 key = ((const u64*)(ws + LSORT_OFF))[(size_t)P * 1024 + j];
    int a = (int)(u32)key;
    float x1, y1, x2, y2; bool valid;
    decode_clip(pred, anch, vs, b, a, x1, y1, x2, y2, valid);
    m = fmaxf(fmaxf(x1, y1), fmaxf(x2, y2));
    ((float4*)(ws + DBOX_OFF))[(size_t)P * 1024 + j] = make_float4(x1, y1, x2, y2);
    ((u32*)(ws + DVAL_OFF))[(size_t)P * 1024 + j] = valid ? 1u : 0u;
    ((float*)(ws + DSC_OFF))[(size_t)P * 1024 + j] = obj[(size_t)b * A_TOT + a];
  }
  for (int off = 32; off; off >>= 1) m = fmaxf(m, __shfl_xor(m, off));
  if ((threadIdx.x & 63) == 0)
    atomicMax((u32*)(ws + MAXC_OFF) + b, __float_as_uint(m));
}

// ---------- 6) stable valid-compaction per level (1 wave each) ----------
__global__ void k_prep2(char* __restrict__ ws) {
  int P = blockIdx.x;
  int lane = threadIdx.x;
  int n = level_n(P % 5);
  int base = 0;
  for (int j0 = 0; j0 < n; j0 += 64) {
    int j = j0 + lane;
    bool inb = j < n;
    u32 v = inb ? ((const u32*)(ws + DVAL_OFF))[(size_t)P * 1024 + j] : 0u;
    u64 m = __ballot(v != 0);
    int r = base + __popcll(m & ((1ull << lane) - 1ull));
    if (v) {
      ((u64*)(ws + LKEY2_OFF))[(size_t)P * 1024 + r] =
          ((const u64*)(ws + LSORT_OFF))[(size_t)P * 1024 + j];
      ((float4*)(ws + LBOX_OFF))[(size_t)P * 1024 + r] =
          ((const float4*)(ws + DBOX_OFF))[(size_t)P * 1024 + j];
      ((float*)(ws + LSC_OFF))[(size_t)P * 1024 + r] =
          ((const float*)(ws + DSC_OFF))[(size_t)P * 1024 + j];
    }
    base += __popcll(m);
  }
  if (lane == 0) ((u32*)(ws + NV_OFF))[P] = (u32)base;
}

__device__ __forceinline__ int lbound(const u64* __restrict__ arr, int n, u64 key) {
  int lo = 0, hi = n;
  while (lo < hi) { int mid = (lo + hi) >> 1; if (arr[mid] < key) lo = mid + 1; else hi = mid; }
  return lo;
}

// ---------- 7) global rank via 5-way merge (binary searches) ----------
__global__ void k_rank(char* __restrict__ ws) {
  int P = blockIdx.x, b = P / 5, l = P % 5;
  int nv = (int)((const u32*)(ws + NV_OFF))[P];
  const u64* lkey = (const u64*)(ws + LKEY2_OFF);
  const u32* nvp = (const u32*)(ws + NV_OFF);
  for (int i = threadIdx.x; i < nv; i += blockDim.x) {
    u64 key = lkey[(size_t)P * 1024 + i];
    int r = i;
    for (int l2 = 0; l2 < 5; ++l2) {
      if (l2 == l) continue;
      int P2 = b * 5 + l2;
      r += lbound(lkey + (size_t)P2 * 1024, (int)nvp[P2], key);
    }
    ((u32*)(ws + RANK_OFF))[(size_t)P * 1024 + i] = (u32)r;
    ((u32*)(ws + GL_OFF))[(size_t)b * 4608 + r] = ((u32)l << 16) | (u32)i;
  }
}

// ---------- 8) suppression bitmask + per-chunk row-nonempty bitmap ----------
__global__ void k_mask(char* __restrict__ ws) {
  int t = blockIdx.x * blockDim.x + threadIdx.x;  // 2*5*1000*16
  if (t >= 160000) return;
  int w = t & 15;
  int rest = t >> 4;
  int i = rest % 1000;
  int l = (rest / 1000) % 5;
  int b = rest / 5000;
  int P = b * 5 + l;
  int n = (int)((const u32*)(ws + NV_OFF))[P];
  int W = (n + 63) >> 6;
  if (i >= n || w >= W) return;
  float M = __uint_as_float(((const u32*)(ws + MAXC_OFF))[b]);
  float maxc = __fadd_rn(M, 1.0f);
  float off = __fmul_rn((float)l, maxc);
  const float4* lbox = (const float4*)(ws + LBOX_OFF) + (size_t)P * 1024;
  float4 bi = lbox[i];
  bi.x = __fadd_rn(bi.x, off); bi.y = __fadd_rn(bi.y, off);
  bi.z = __fadd_rn(bi.z, off); bi.w = __fadd_rn(bi.w, off);
  float ai = __fmul_rn(__fsub_rn(bi.z, bi.x), __fsub_rn(bi.w, bi.y));
  u64 word = 0;
  int j0 = w << 6;
  int jn = min(64, n - j0);
  for (int jj = 0; jj < jn; ++jj) {
    float4 bj = lbox[j0 + jj];
    bj.x = __fadd_rn(bj.x, off); bj.y = __fadd_rn(bj.y, off);
    bj.z = __fadd_rn(bj.z, off); bj.w = __fadd_rn(bj.w, off);
    float xx1 = fmaxf(bi.x, bj.x);
    float yy1 = fmaxf(bi.y, bj.y);
    float xx2 = fminf(bi.z, bj.z);
    float yy2 = fminf(bi.w, bj.w);
    float iw = fmaxf(__fsub_rn(xx2, xx1), 0.0f);
    float ih = fmaxf(__fsub_rn(yy2, yy1), 0.0f);
    float inter = __fmul_rn(iw, ih);
    float aj = __fmul_rn(__fsub_rn(bj.z, bj.x), __fsub_rn(bj.w, bj.y));
    float den = __fadd_rn(__fsub_rn(__fadd_rn(ai, aj), inter), 1e-9f);
    float iou = __fdiv_rn(inter, den);
    if (iou > 0.7f) word |= (1ull << jj);
  }
  if (i >= j0 && i < j0 + 64) word &= ~(1ull << (i - j0));  // zero diagonal
  ((u64*)(ws + MASK_OFF))[(size_t)P * 16000 + (size_t)i * W + w] = word;
  if (word)
    atomicOr((u64*)(ws + CHUNKANY_OFF) + (size_t)P * 16 + (i >> 6), 1ull << (i & 63));
}

// ---------- 9) chunked greedy scan; keep bits -> rank bitmap ----------
__global__ void k_scan(char* __restrict__ ws) {
  __shared__ u64 ldsk[16];
  int P = blockIdx.x, b = P / 5;
  int lane = threadIdx.x;
  int n = (int)((const u32*)(ws + NV_OFF))[P];
  int W = (n + 63) >> 6;
  const u64* maskg = (const u64*)(ws + MASK_OFF) + (size_t)P * 16000;
  const u64* chunkany = (const u64*)(ws + CHUNKANY_OFF) + (size_t)P * 16;

  u64 removed = 0, keepw = 0;       // all entries valid now
  int NC = (n + 63) >> 6;
  for (int c = 0; c < NC; ++c) {
    int rb = c << 6;
    int rows = min(64, n - rb);
    u64 rowsmask = (rows == 64) ? ~0ull : ((1ull << rows) - 1ull);
    u64 curw = __shfl(removed, c);
    u64 cand = ~curw & rowsmask;
    u64 anyrows = chunkany[c] & cand;
    u64 keptbits;
    if (anyrows == 0ull) {
      keptbits = cand;
    } else {
      u64 diag = (lane < rows) ? maskg[(size_t)(rb + lane) * W + c] : 0ull;
      u64 diagnz = __ballot(diag != 0ull);
      if ((diagnz & cand) == 0ull) {
        keptbits = cand;
      } else {
        u64 remw = curw | ~rowsmask;
        u64 kept = 0;
        for (int r = 0; r < rows; ++r) {
          u64 dr = __shfl(diag, r);
          bool k = ((remw >> r) & 1ull) == 0ull;
          u64 sel = k ? ~0ull : 0ull;
          remw |= dr & sel;
          kept |= ((u64)(k ? 1 : 0)) << r;
        }
        keptbits = kept;
      }
      u64 todo = keptbits & chunkany[c];
      while (todo) {
        int r = __builtin_ctzll(todo);
        todo &= todo - 1;
        u64 rowv = (lane < W) ? maskg[(size_t)(rb + r) * W + lane] : 0ull;
        removed |= rowv;
      }
    }
    if (lane == c) keepw |= keptbits;
  }
  if (lane < 16) ldsk[lane] = keepw;
  __syncthreads();
  const u32* rank = (const u32*)(ws + RANK_OFF) + (size_t)P * 1024;
  for (int i = lane; i < n; i += 64) {
    if ((ldsk[i >> 6] >> (i & 63)) & 1ull) {
      u32 r = rank[i];
      atomicOr((u64*)(ws + KB_OFF) + (size_t)b * 128 + (r >> 6), 1ull << (r & 63));
    }
  }
}

// ---------- 10) prefix-popcount over rank bitmap; write outputs ----------
__global__ void k_finalize(float* __restrict__ out, char* __restrict__ ws) {
  __shared__ u64 kb[72];
  int b = blockIdx.x;
  int lane = threadIdx.x;
  if (lane < 72) kb[lane] = ((const u64*)(ws + KB_OFF))[(size_t)b * 128 + lane];
  __syncthreads();
  int base = 0;
  for (int w = 0; w < 72; ++w) {
    u64 word = kb[w];
    bool mine = (word >> lane) & 1ull;
    int slot = base + __popcll(word & ((1ull << lane) - 1ull));
    if (mine && slot < KTOP) {
      int r = w * 64 + lane;
      u32 g = ((const u32*)(ws + GL_OFF))[(size_t)b * 4608 + r];
      int l = g >> 16, i = g & 0xFFFF;
      int P = b * 5 + l;
      float4 bx = ((const float4*)(ws + LBOX_OFF))[(size_t)P * 1024 + i];
      float s = ((const float*)(ws + LSC_OFF))[(size_t)P * 1024 + i];
      float* ob = out + ((size_t)b * KTOP + slot) * 4;
      ob[0] = bx.x; ob[1] = bx.y; ob[2] = bx.z; ob[3] = bx.w;
      out[8000 + (size_t)b * KTOP + slot] = s;
    }
    base += __popcll(word);
  }
}

extern "C" void kernel_launch(void* const* d_in, const int* in_sizes, int n_in,
                              void* d_out, int out_size, void* d_ws, size_t ws_size,
                              hipStream_t stream) {
  const float* pred = (const float*)d_in[0];
  const float* obj  = (const float*)d_in[1];
  const float* anch = (const float*)d_in[2];
  const float* vs   = (const float*)d_in[3];
  float* out = (float*)d_out;
  char* ws = (char*)d_ws;
  (void)in_sizes; (void)n_in; (void)out_size; (void)ws_size;

  hipMemsetAsync(ws, 0, ZERO_BYTES, stream);
  hipMemsetAsync(d_out, 0, 10000 * sizeof(float), stream);

  int gBA = (BS * A_TOT + 255) / 256;
  k_hist    <<<gBA, 256, 0, stream>>>(obj, ws);
  k_cutoff  <<<8,   256, 0, stream>>>(ws);
  k_compact <<<gBA, 256, 0, stream>>>(obj, ws);
  k_sortcand<<<10,  512, 0, stream>>>(obj, ws);
  k_decode  <<<40,  256, 0, stream>>>(pred, obj, anch, vs, ws);
  k_prep2   <<<10,   64, 0, stream>>>(ws);
  k_rank    <<<10,  128, 0, stream>>>(ws);
  k_mask    <<<625, 256, 0, stream>>>(ws);
  k_scan    <<<10,   64, 0, stream>>>(ws);
  k_finalize<<<2,    64, 0, stream>>>(out, ws);
}

// Round 4
// 321.474 us; speedup vs baseline: 2.4888x; 1.2559x over previous
//
#include <hip/hip_runtime.h>

typedef unsigned int u32;
typedef unsigned long long u64;

#define A_TOT    159882
#define BS       2
#define KTOP     1000
#define CAND_CAP 4096
#define CHUNK    4096          // anchors per k_compact block
#define EPT      16            // elements per thread in k_compact (CHUNK/256)

// ---- workspace layout (bytes) ----
static const size_t HIST_OFF   = 0;           // u32[8*65536] = 2 MB
static const size_t CUT_OFF    = 2097152;     // u32[8]
static const size_t CCNT_OFF   = 2097184;     // u32[8]
static const size_t MAXC_OFF   = 2097216;     // u32[2]
static const size_t NV_OFF     = 2097224;     // u32[10]
static const size_t CHUNKANY_OFF = 2097280;   // u64[10*16] = 1280
static const size_t KB_OFF     = 2098560;     // u64[2*128] = 2048
static const size_t ZERO_END   = 2100608;     // k_zero covers [0, ZERO_END)
static const size_t CAND_OFF   = 2101248;     // u64[8*4096]
static const size_t LSORT_OFF  = 2363392;     // u64[10*1024]
static const size_t DBOX_OFF   = 2445312;     // float4[10*1024]
static const size_t DVAL_OFF   = 2609152;     // u32[10*1024]
static const size_t DSC_OFF    = 2650112;     // float[10*1024]
static const size_t LKEY2_OFF  = 2691072;     // u64[10*1024]
static const size_t LBOX_OFF   = 2772992;     // float4[10*1024]
static const size_t LSC_OFF    = 2936832;     // float[10*1024]
static const size_t RANK_OFF   = 2977792;     // u32[10*1024]
static const size_t GL_OFF     = 3018752;     // u32[2*4608]
static const size_t MASK_OFF   = 3055616;     // u64[10*16000]
// total ~4.34 MB

__device__ __forceinline__ int level_of(int a) {
  if (a < 120000) return 0;
  if (a < 150000) return 1;
  if (a < 157500) return 2;
  if (a < 159375) return 3;
  return 4;
}
__device__ __forceinline__ int level_n(int l) { return (l == 4) ? 507 : 1000; }

// monotone decreasing transform: smaller d == larger score; d(-inf)=0xFF800000
__device__ __forceinline__ u32 dkey(float s) {
  u32 b = __float_as_uint(s);
  return (b & 0x80000000u) ? b : (~b & 0x7FFFFFFFu);
}

// bit-exact replica of reference decode + clip + min-size check
__device__ __forceinline__ void decode_clip(const float* __restrict__ pred,
                                            const float* __restrict__ anch,
                                            const float* __restrict__ vs,
                                            int b, int a,
                                            float& x1c, float& y1c, float& x2c, float& y2c,
                                            bool& valid) {
  const float* pp = pred + ((size_t)b * A_TOT + (size_t)a) * 4;
  const float* aa = anch + (size_t)a * 4;
  float ax1 = aa[0], ay1 = aa[1], ax2 = aa[2], ay2 = aa[3];
  float px = pp[0], py = pp[1], pw = pp[2], ph = pp[3];
  float aw  = __fsub_rn(ax2, ax1);
  float ah  = __fsub_rn(ay2, ay1);
  float acx = __fadd_rn(ax1, __fmul_rn(0.5f, aw));
  float acy = __fadd_rn(ay1, __fmul_rn(0.5f, ah));
  float cx  = __fadd_rn(acx, __fmul_rn(px, aw));
  float cy  = __fadd_rn(acy, __fmul_rn(py, ah));
  float w   = __fmul_rn(expf(pw), aw);
  float h   = __fmul_rn(expf(ph), ah);
  float x1  = __fsub_rn(cx, __fmul_rn(0.5f, w));
  float y1  = __fsub_rn(cy, __fmul_rn(0.5f, h));
  float x2  = __fadd_rn(x1, w);
  float y2  = __fadd_rn(y1, h);
  float Wv = vs[b * 2 + 0], Hv = vs[b * 2 + 1];
  x1c = fminf(fmaxf(x1, 0.0f), Wv);
  y1c = fminf(fmaxf(y1, 0.0f), Hv);
  x2c = fminf(fmaxf(x2, 0.0f), Wv);
  y2c = fminf(fmaxf(y2, 0.0f), Hv);
  valid = (__fsub_rn(x2c, x1c) > 0.001f) && (__fsub_rn(y2c, y1c) > 0.001f);
}

// ---------- 0) zero hist + control (replaces big memset) ----------
__global__ void k_zero(char* __restrict__ ws) {
  size_t i = ((size_t)blockIdx.x * blockDim.x + threadIdx.x) * 16;
  if (i < ZERO_END)
    *(uint4*)(ws + i) = make_uint4(0, 0, 0, 0);
}

// ---------- 1) per-(image,level<4) 16-bit score histogram ----------
__global__ void k_hist(const float* __restrict__ obj, char* __restrict__ ws) {
  int t = blockIdx.x * blockDim.x + threadIdx.x;
  if (t >= BS * A_TOT) return;
  int b = t / A_TOT, a = t % A_TOT;
  int l = level_of(a);
  if (l >= 4) return;
  u32 d = dkey(obj[t]);
  atomicAdd((u32*)(ws + HIST_OFF) + (size_t)(b * 4 + l) * 65536 + (d >> 16), 1u);
}

// ---------- 2) cutoff bucket for top-1000 (parallel prefix scans) ----------
__global__ void k_cutoff(char* __restrict__ ws) {
  int b = blockIdx.x >> 2, l = blockIdx.x & 3;
  const u32* hist = (const u32*)(ws + HIST_OFF) + (size_t)(b * 4 + l) * 65536;
  __shared__ u32 incl[256];
  __shared__ u32 sc_c, sc_base;
  int t = threadIdx.x;
  u32 s = 0;
  for (int q = 0; q < 256; ++q) s += hist[t * 256 + q];
  incl[t] = s; __syncthreads();
  for (int d = 1; d < 256; d <<= 1) {
    u32 v = (t >= d) ? incl[t - d] : 0u; __syncthreads();
    incl[t] += v; __syncthreads();
  }
  if (incl[t] >= KTOP && (t == 0 || incl[t - 1] < KTOP)) {
    sc_c = (u32)t; sc_base = (t == 0) ? 0u : incl[t - 1];
  }
  __syncthreads();
  u32 c = sc_c, base = sc_base;
  u32 v2 = hist[c * 256 + t];
  __syncthreads();
  incl[t] = v2; __syncthreads();
  for (int d = 1; d < 256; d <<= 1) {
    u32 v = (t >= d) ? incl[t - d] : 0u; __syncthreads();
    incl[t] += v; __syncthreads();
  }
  if (base + incl[t] >= KTOP && (t == 0 || base + incl[t - 1] < KTOP))
    ((u32*)(ws + CUT_OFF))[b * 4 + l] = c * 256 + (u32)t;
}

// ---------- 3) compact candidates: block-aggregated allocation ----------
__global__ void k_compact(const float* __restrict__ obj, char* __restrict__ ws) {
  __shared__ u32 lcnt[8];     // per-segment block-local count / cursor
  __shared__ u32 gbase[8];    // per-segment global base
  __shared__ u32 lcut[8];
  int tid = threadIdx.x, lane = tid & 63;
  if (tid < 8) { lcnt[tid] = 0; lcut[tid] = ((const u32*)(ws + CUT_OFF))[tid]; }
  __syncthreads();

  int base_t = blockIdx.x * CHUNK;
  u32 dv[EPT], slotv[EPT];
  u32 passmask = 0;

#pragma unroll
  for (int it = 0; it < EPT; ++it) {
    int t = base_t + it * 256 + tid;
    bool pass = false; u32 seg = 0; u32 d = 0;
    if (t < BS * A_TOT) {
      int b = t / A_TOT, a = t % A_TOT;
      int l = level_of(a);
      if (l < 4) {
        seg = (u32)(b * 4 + l);
        d = dkey(obj[t]);
        pass = (d >> 16) <= lcut[seg];
      }
    }
    dv[it] = d;
    u32 slot = 0;
    u64 rem = __ballot(pass);
    while (rem) {
      int ld = __builtin_ctzll(rem);
      u32 s0 = __shfl(seg, ld);
      u64 grp = __ballot(pass && seg == s0);
      u32 wb = 0;
      if (lane == ld) wb = atomicAdd(&lcnt[s0], (u32)__popcll(grp));
      wb = __shfl(wb, ld);
      if (pass && seg == s0)
        slot = wb + (u32)__popcll(grp & ((1ull << lane) - 1ull));
      rem &= ~grp;
    }
    slotv[it] = slot;
    if (pass) passmask |= (1u << it);
  }
  __syncthreads();
  if (tid < 8)
    gbase[tid] = lcnt[tid] ? atomicAdd((u32*)(ws + CCNT_OFF) + tid, lcnt[tid]) : 0u;
  __syncthreads();

#pragma unroll
  for (int it = 0; it < EPT; ++it) {
    if ((passmask >> it) & 1u) {
      int t = base_t + it * 256 + tid;
      int b = t / A_TOT, a = t % A_TOT;
      int l = level_of(a);
      u32 seg = (u32)(b * 4 + l);
      u32 gslot = gbase[seg] + slotv[it];
      if (gslot < CAND_CAP)
        ((u64*)(ws + CAND_OFF))[(size_t)seg * CAND_CAP + gslot] =
            ((u64)dv[it] << 32) | (u32)a;
    }
  }
}

__device__ __forceinline__ void bitonic_u64(u64* arr, int N, int t, int nt) {
  for (int k = 2; k <= N; k <<= 1) {
    for (int j = k >> 1; j > 0; j >>= 1) {
      __syncthreads();
      for (int i = t; i < N; i += nt) {
        int ixj = i ^ j;
        if (ixj > i) {
          u64 x = arr[i], y = arr[ixj];
          bool up = ((i & k) == 0);
          if (up ? (x > y) : (x < y)) { arr[i] = y; arr[ixj] = x; }
        }
      }
    }
  }
  __syncthreads();
}

// ---------- 4) per-(image,level) sorted key lists (dynamic N) ----------
__global__ void k_sortcand(const float* __restrict__ obj, char* __restrict__ ws) {
  __shared__ u64 arr[CAND_CAP];   // 32 KB
  int P = blockIdx.x, b = P / 5, l = P % 5;
  int t = threadIdx.x, nt = blockDim.x;
  int N, n_out;
  if (l < 4) {
    u32 cnt = ((const u32*)(ws + CCNT_OFF))[b * 4 + l];
    if (cnt > CAND_CAP) cnt = CAND_CAP;
    N = 1024; while (N < (int)cnt) N <<= 1;
    const u64* cand = (const u64*)(ws + CAND_OFF) + (size_t)(b * 4 + l) * CAND_CAP;
    for (int i = t; i < N; i += nt) arr[i] = (i < (int)cnt) ? cand[i] : ~0ull;
    n_out = KTOP;
  } else {
    N = 512;
    for (int i = t; i < N; i += nt) {
      if (i < 507) {
        int a = 159375 + i;
        u32 d = dkey(obj[(size_t)b * A_TOT + a]);
        arr[i] = ((u64)d << 32) | (u32)a;
      } else arr[i] = ~0ull;
    }
    n_out = 507;
  }
  bitonic_u64(arr, N, t, nt);
  u64* lsort = (u64*)(ws + LSORT_OFF) + (size_t)P * 1024;
  for (int i = t; i < n_out; i += nt) lsort[i] = arr[i];
}

// ---------- 5) fully-parallel decode of all selected entries ----------
__global__ void k_decode(const float* __restrict__ pred, const float* __restrict__ obj,
                         const float* __restrict__ anch, const float* __restrict__ vs,
                         char* __restrict__ ws) {
  int t = blockIdx.x * blockDim.x + threadIdx.x;   // 10*1024
  int P = t >> 10, j = t & 1023;
  int b = P / 5, l = P % 5;
  int n = level_n(l);
  float m = 0.0f;
  if (j < n) {
    u64 key = ((const u64*)(ws + LSORT_OFF))[(size_t)P * 1024 + j];
    int a = (int)(u32)key;
    float x1, y1, x2, y2; bool valid;
    decode_clip(pred, anch, vs, b, a, x1, y1, x2, y2, valid);
    m = fmaxf(fmaxf(x1, y1), fmaxf(x2, y2));
    ((float4*)(ws + DBOX_OFF))[(size_t)P * 1024 + j] = make_float4(x1, y1, x2, y2);
    ((u32*)(ws + DVAL_OFF))[(size_t)P * 1024 + j] = valid ? 1u : 0u;
    ((float*)(ws + DSC_OFF))[(size_t)P * 1024 + j] = obj[(size_t)b * A_TOT + a];
  }
  for (int off = 32; off; off >>= 1) m = fmaxf(m, __shfl_xor(m, off));
  if ((threadIdx.x & 63) == 0)
    atomicMax((u32*)(ws + MAXC_OFF) + b, __float_as_uint(m));
}

// ---------- 6) stable valid-compaction per level (1 wave each) ----------
__global__ void k_prep2(char* __restrict__ ws) {
  int P = blockIdx.x;
  int lane = threadIdx.x;
  int n = level_n(P % 5);
  int base = 0;
  for (int j0 = 0; j0 < n; j0 += 64) {
    int j = j0 + lane;
    bool inb = j < n;
    u32 v = inb ? ((const u32*)(ws + DVAL_OFF))[(size_t)P * 1024 + j] : 0u;
    u64 m = __ballot(v != 0);
    int r = base + __popcll(m & ((1ull << lane) - 1ull));
    if (v) {
      ((u64*)(ws + LKEY2_OFF))[(size_t)P * 1024 + r] =
          ((const u64*)(ws + LSORT_OFF))[(size_t)P * 1024 + j];
      ((float4*)(ws + LBOX_OFF))[(size_t)P * 1024 + r] =
          ((const float4*)(ws + DBOX_OFF))[(size_t)P * 1024 + j];
      ((float*)(ws + LSC_OFF))[(size_t)P * 1024 + r] =
          ((const float*)(ws + DSC_OFF))[(size_t)P * 1024 + j];
    }
    base += __popcll(m);
  }
  if (lane == 0) ((u32*)(ws + NV_OFF))[P] = (u32)base;
}

__device__ __forceinline__ int lbound(const u64* __restrict__ arr, int n, u64 key) {
  int lo = 0, hi = n;
  while (lo < hi) { int mid = (lo + hi) >> 1; if (arr[mid] < key) lo = mid + 1; else hi = mid; }
  return lo;
}

// ---------- 7) global rank via 5-way merge (binary searches) ----------
__global__ void k_rank(char* __restrict__ ws) {
  int P = blockIdx.x, b = P / 5, l = P % 5;
  int nv = (int)((const u32*)(ws + NV_OFF))[P];
  const u64* lkey = (const u64*)(ws + LKEY2_OFF);
  const u32* nvp = (const u32*)(ws + NV_OFF);
  for (int i = threadIdx.x; i < nv; i += blockDim.x) {
    u64 key = lkey[(size_t)P * 1024 + i];
    int r = i;
    for (int l2 = 0; l2 < 5; ++l2) {
      if (l2 == l) continue;
      int P2 = b * 5 + l2;
      r += lbound(lkey + (size_t)P2 * 1024, (int)nvp[P2], key);
    }
    ((u32*)(ws + RANK_OFF))[(size_t)P * 1024 + i] = (u32)r;
    ((u32*)(ws + GL_OFF))[(size_t)b * 4608 + r] = ((u32)l << 16) | (u32)i;
  }
}

// ---------- 8) suppression bitmask + per-chunk row-nonempty bitmap ----------
__global__ void k_mask(char* __restrict__ ws) {
  int t = blockIdx.x * blockDim.x + threadIdx.x;  // 2*5*1000*16
  if (t >= 160000) return;
  int w = t & 15;
  int rest = t >> 4;
  int i = rest % 1000;
  int l = (rest / 1000) % 5;
  int b = rest / 5000;
  int P = b * 5 + l;
  int n = (int)((const u32*)(ws + NV_OFF))[P];
  int W = (n + 63) >> 6;
  if (i >= n || w >= W) return;
  float M = __uint_as_float(((const u32*)(ws + MAXC_OFF))[b]);
  float maxc = __fadd_rn(M, 1.0f);
  float off = __fmul_rn((float)l, maxc);
  const float4* lbox = (const float4*)(ws + LBOX_OFF) + (size_t)P * 1024;
  float4 bi = lbox[i];
  bi.x = __fadd_rn(bi.x, off); bi.y = __fadd_rn(bi.y, off);
  bi.z = __fadd_rn(bi.z, off); bi.w = __fadd_rn(bi.w, off);
  float ai = __fmul_rn(__fsub_rn(bi.z, bi.x), __fsub_rn(bi.w, bi.y));
  u64 word = 0;
  int j0 = w << 6;
  int jn = min(64, n - j0);
  for (int jj = 0; jj < jn; ++jj) {
    float4 bj = lbox[j0 + jj];
    bj.x = __fadd_rn(bj.x, off); bj.y = __fadd_rn(bj.y, off);
    bj.z = __fadd_rn(bj.z, off); bj.w = __fadd_rn(bj.w, off);
    float xx1 = fmaxf(bi.x, bj.x);
    float yy1 = fmaxf(bi.y, bj.y);
    float xx2 = fminf(bi.z, bj.z);
    float yy2 = fminf(bi.w, bj.w);
    float iw = fmaxf(__fsub_rn(xx2, xx1), 0.0f);
    float ih = fmaxf(__fsub_rn(yy2, yy1), 0.0f);
    float inter = __fmul_rn(iw, ih);
    float aj = __fmul_rn(__fsub_rn(bj.z, bj.x), __fsub_rn(bj.w, bj.y));
    float den = __fadd_rn(__fsub_rn(__fadd_rn(ai, aj), inter), 1e-9f);
    float iou = __fdiv_rn(inter, den);
    if (iou > 0.7f) word |= (1ull << jj);
  }
  if (i >= j0 && i < j0 + 64) word &= ~(1ull << (i - j0));  // zero diagonal
  ((u64*)(ws + MASK_OFF))[(size_t)P * 16000 + (size_t)i * W + w] = word;
  if (word)
    atomicOr((u64*)(ws + CHUNKANY_OFF) + (size_t)P * 16 + (i >> 6), 1ull << (i & 63));
}

// ---------- 9) chunked greedy scan; keep bits -> rank bitmap ----------
__global__ void k_scan(char* __restrict__ ws) {
  __shared__ u64 ldsk[16];
  int P = blockIdx.x, b = P / 5;
  int lane = threadIdx.x;
  int n = (int)((const u32*)(ws + NV_OFF))[P];
  int W = (n + 63) >> 6;
  const u64* maskg = (const u64*)(ws + MASK_OFF) + (size_t)P * 16000;
  const u64* chunkany = (const u64*)(ws + CHUNKANY_OFF) + (size_t)P * 16;

  u64 removed = 0, keepw = 0;       // all entries valid now
  int NC = (n + 63) >> 6;
  for (int c = 0; c < NC; ++c) {
    int rb = c << 6;
    int rows = min(64, n - rb);
    u64 rowsmask = (rows == 64) ? ~0ull : ((1ull << rows) - 1ull);
    u64 curw = __shfl(removed, c);
    u64 cand = ~curw & rowsmask;
    u64 anyrows = chunkany[c] & cand;
    u64 keptbits;
    if (anyrows == 0ull) {
      keptbits = cand;
    } else {
      u64 diag = (lane < rows) ? maskg[(size_t)(rb + lane) * W + c] : 0ull;
      u64 diagnz = __ballot(diag != 0ull);
      if ((diagnz & cand) == 0ull) {
        keptbits = cand;
      } else {
        u64 remw = curw | ~rowsmask;
        u64 kept = 0;
        for (int r = 0; r < rows; ++r) {
          u64 dr = __shfl(diag, r);
          bool k = ((remw >> r) & 1ull) == 0ull;
          u64 sel = k ? ~0ull : 0ull;
          remw |= dr & sel;
          kept |= ((u64)(k ? 1 : 0)) << r;
        }
        keptbits = kept;
      }
      u64 todo = keptbits & chunkany[c];
      while (todo) {
        int r = __builtin_ctzll(todo);
        todo &= todo - 1;
        u64 rowv = (lane < W) ? maskg[(size_t)(rb + r) * W + lane] : 0ull;
        removed |= rowv;
      }
    }
    if (lane == c) keepw |= keptbits;
  }
  if (lane < 16) ldsk[lane] = keepw;
  __syncthreads();
  const u32* rank = (const u32*)(ws + RANK_OFF) + (size_t)P * 1024;
  for (int i = lane; i < n; i += 64) {
    if ((ldsk[i >> 6] >> (i & 63)) & 1ull) {
      u32 r = rank[i];
      atomicOr((u64*)(ws + KB_OFF) + (size_t)b * 128 + (r >> 6), 1ull << (r & 63));
    }
  }
}

// ---------- 10) zero-fill out; prefix-popcount over rank bitmap; write ----------
__global__ void k_finalize(float* __restrict__ out, char* __restrict__ ws) {
  __shared__ u64 kb[72];
  int b = blockIdx.x;
  int lane = threadIdx.x;
  // zero this image's output slice (d_out is poisoned before every launch)
  for (int i = lane; i < 4000; i += 64) out[(size_t)b * 4000 + i] = 0.0f;
  for (int i = lane; i < 1000; i += 64) out[8000 + (size_t)b * 1000 + i] = 0.0f;
  if (lane < 72) kb[lane] = ((const u64*)(ws + KB_OFF))[(size_t)b * 128 + lane];
  __syncthreads();
  int base = 0;
  for (int w = 0; w < 72; ++w) {
    u64 word = kb[w];
    bool mine = (word >> lane) & 1ull;
    int slot = base + __popcll(word & ((1ull << lane) - 1ull));
    if (mine && slot < KTOP) {
      int r = w * 64 + lane;
      u32 g = ((const u32*)(ws + GL_OFF))[(size_t)b * 4608 + r];
      int l = g >> 16, i = g & 0xFFFF;
      int P = b * 5 + l;
      float4 bx = ((const float4*)(ws + LBOX_OFF))[(size_t)P * 1024 + i];
      float s = ((const float*)(ws + LSC_OFF))[(size_t)P * 1024 + i];
      float* ob = out + ((size_t)b * KTOP + slot) * 4;
      ob[0] = bx.x; ob[1] = bx.y; ob[2] = bx.z; ob[3] = bx.w;
      out[8000 + (size_t)b * KTOP + slot] = s;
    }
    base += __popcll(word);
  }
}

extern "C" void kernel_launch(void* const* d_in, const int* in_sizes, int n_in,
                              void* d_out, int out_size, void* d_ws, size_t ws_size,
                              hipStream_t stream) {
  const float* pred = (const float*)d_in[0];
  const float* obj  = (const float*)d_in[1];
  const float* anch = (const float*)d_in[2];
  const float* vs   = (const float*)d_in[3];
  float* out = (float*)d_out;
  char* ws = (char*)d_ws;
  (void)in_sizes; (void)n_in; (void)out_size; (void)ws_size;

  int gBA = (BS * A_TOT + 255) / 256;
  int gZ  = (int)((ZERO_END / 16 + 255) / 256);
  int gC  = (BS * A_TOT + CHUNK - 1) / CHUNK;

  k_zero    <<<gZ,  256, 0, stream>>>(ws);
  k_hist    <<<gBA, 256, 0, stream>>>(obj, ws);
  k_cutoff  <<<8,   256, 0, stream>>>(ws);
  k_compact <<<gC,  256, 0, stream>>>(obj, ws);
  k_sortcand<<<10,  512, 0, stream>>>(obj, ws);
  k_decode  <<<40,  256, 0, stream>>>(pred, obj, anch, vs, ws);
  k_prep2   <<<10,   64, 0, stream>>>(ws);
  k_rank    <<<10,  128, 0, stream>>>(ws);
  k_mask    <<<625, 256, 0, stream>>>(ws);
  k_scan    <<<10,   64, 0, stream>>>(ws);
  k_finalize<<<2,    64, 0, stream>>>(out, ws);
}